// Round 1
// baseline (297.035 us; speedup 1.0000x reference)
//
#include <hip/hip_runtime.h>

// GuidedAttentionL1Loss on MI355X.
// Inputs: 0=logits[B,2] f32, 1=labels[B] i32, 2=attention_weights[T] f32,
//         3=params[P] f32, 4=xpos[T] f32 (UNUSED - recomputed analytically),
//         5=segment_ids[T] i32 (UNUSED - segments are contiguous; starts from scan),
//         6=lengths[B] i32
// Output: [loss, nll] f32.
//
// ws layout: accs[0]=awp_sum, accs[1]=abs_sum, accs[2]=nll_sum(logp), then at
// +64 bytes: starts[B] (int32, exclusive prefix sum of lengths).

#define TPB 256

__device__ __forceinline__ float blockReduceSum(float v, float* sm) {
  // wave64 shuffle reduce, then 4-wave LDS combine. blockDim.x must be 256.
  #pragma unroll
  for (int off = 32; off > 0; off >>= 1) v += __shfl_down(v, off, 64);
  const int lane = threadIdx.x & 63;
  const int wid  = threadIdx.x >> 6;
  if (lane == 0) sm[wid] = v;
  __syncthreads();
  float s = sm[0] + sm[1] + sm[2] + sm[3];
  __syncthreads();  // protect sm for the next reduction
  return s;
}

// ---------------------------------------------------------------- kernel A --
__global__ __launch_bounds__(TPB)
void setup_kernel(const float* __restrict__ logits, const int* __restrict__ labels,
                  const int* __restrict__ lengths, int nseg,
                  int* __restrict__ starts, float* __restrict__ accs) {
  __shared__ int ssum[TPB];
  __shared__ float sm[4];
  const int t = threadIdx.x;
  if (t < 2) accs[t] = 0.0f;  // awp_sum, abs_sum

  // exclusive prefix scan of lengths -> starts
  const int per = (nseg + TPB - 1) / TPB;  // 32 for B=8192
  const int base = t * per;
  int local = 0;
  for (int j = 0; j < per; j++) {
    int idx = base + j;
    if (idx < nseg) local += lengths[idx];
  }
  ssum[t] = local;
  __syncthreads();
  if (t == 0) {
    int run = 0;
    for (int i = 0; i < TPB; i++) { int v = ssum[i]; ssum[i] = run; run += v; }
  }
  __syncthreads();
  int run = ssum[t];
  for (int j = 0; j < per; j++) {
    int idx = base + j;
    if (idx < nseg) { starts[idx] = run; run += lengths[idx]; }
  }

  // NLL sum: sum over segments of logp[label] (2-class log-softmax)
  float acc = 0.0f;
  for (int b = t; b < nseg; b += TPB) {
    float l0 = logits[2 * b], l1 = logits[2 * b + 1];
    int lab = labels[b];
    float m = fmaxf(l0, l1);
    float lse = m + logf(expf(l0 - m) + expf(l1 - m));
    acc += (lab ? l1 : l0) - lse;
  }
  float tot = blockReduceSum(acc, sm);
  if (t == 0) accs[2] = tot;
}

// ------------------------------------------------------------ segment body --
// NC = number of float4 chunks per thread (1 for len=1024, 3 for len=3072).
template <int NC>
__device__ __forceinline__ void seg_body(const float4* __restrict__ w4, int start4,
                                         int len, int lab, float* __restrict__ awp_acc,
                                         float* sm) {
  const float inv_len = 1.0f / (float)len;
  float4 wv[NC], rv[NC];
  float aw = 0.0f, axw = 0.0f;
  #pragma unroll
  for (int k = 0; k < NC; k++) {
    const int vi = (k << 8) + threadIdx.x;  // float4 index in segment
    wv[k] = w4[start4 + vi];
    const int i0 = vi << 2;
    aw += wv[k].x + wv[k].y + wv[k].z + wv[k].w;
    axw = fmaf((float)(i0 + 1) * inv_len, wv[k].x, axw);
    axw = fmaf((float)(i0 + 2) * inv_len, wv[k].y, axw);
    axw = fmaf((float)(i0 + 3) * inv_len, wv[k].z, axw);
    axw = fmaf((float)(i0 + 4) * inv_len, wv[k].w, axw);
  }
  const float sum_w  = blockReduceSum(aw, sm);
  const float sum_xw = blockReduceSum(axw, sm);
  const float mean = sum_xw / sum_w;
  // std = (lab==1 ? 1.0 : 1000.0)/len  ->  invstd = len * (lab==1 ? 1 : 1e-3)
  const float invstd = (float)len * (lab == 1 ? 1.0f : 0.001f);
  const float rn = 0.39894228040143267f * invstd;  // 1/(std*sqrt(2pi))
  float ar = 0.0f;
  #pragma unroll
  for (int k = 0; k < NC; k++) {
    const int i0 = ((k << 8) + threadIdx.x) << 2;
    float z0 = ((float)(i0 + 1) * inv_len - mean) * invstd;
    float z1 = ((float)(i0 + 2) * inv_len - mean) * invstd;
    float z2 = ((float)(i0 + 3) * inv_len - mean) * invstd;
    float z3 = ((float)(i0 + 4) * inv_len - mean) * invstd;
    rv[k].x = __expf(-0.5f * z0 * z0) * rn;
    rv[k].y = __expf(-0.5f * z1 * z1) * rn;
    rv[k].z = __expf(-0.5f * z2 * z2) * rn;
    rv[k].w = __expf(-0.5f * z3 * z3) * rn;
    ar += rv[k].x + rv[k].y + rv[k].z + rv[k].w;
  }
  const float r_sum = blockReduceSum(ar, sm);
  const float rinv = 1.0f / (r_sum + 1e-6f);
  float ad = 0.0f;
  #pragma unroll
  for (int k = 0; k < NC; k++) {
    float d0 = wv[k].x - rv[k].x * rinv;
    float d1 = wv[k].y - rv[k].y * rinv;
    float d2 = wv[k].z - rv[k].z * rinv;
    float d3 = wv[k].w - rv[k].w * rinv;
    ad = fmaf(d0, d0, ad); ad = fmaf(d1, d1, ad);
    ad = fmaf(d2, d2, ad); ad = fmaf(d3, d3, ad);
  }
  const float dsum = blockReduceSum(ad, sm);
  if (threadIdx.x == 0) atomicAdd(awp_acc, dsum * inv_len);
}

// Generic fallback for unexpected lengths (re-reads w; never hit for this setup).
__device__ void seg_generic(const float* __restrict__ w, int start, int len, int lab,
                            float* __restrict__ awp_acc, float* sm) {
  const float inv_len = 1.0f / (float)len;
  float aw = 0.0f, axw = 0.0f;
  for (int i = threadIdx.x; i < len; i += TPB) {
    float wv = w[start + i];
    aw += wv;
    axw = fmaf((float)(i + 1) * inv_len, wv, axw);
  }
  const float sum_w = blockReduceSum(aw, sm);
  const float sum_xw = blockReduceSum(axw, sm);
  const float mean = sum_xw / sum_w;
  const float invstd = (float)len * (lab == 1 ? 1.0f : 0.001f);
  const float rn = 0.39894228040143267f * invstd;
  float ar = 0.0f;
  for (int i = threadIdx.x; i < len; i += TPB) {
    float z = ((float)(i + 1) * inv_len - mean) * invstd;
    ar += __expf(-0.5f * z * z) * rn;
  }
  const float r_sum = blockReduceSum(ar, sm);
  const float rinv = 1.0f / (r_sum + 1e-6f);
  float ad = 0.0f;
  for (int i = threadIdx.x; i < len; i += TPB) {
    float z = ((float)(i + 1) * inv_len - mean) * invstd;
    float rh = __expf(-0.5f * z * z) * rn;
    float d = w[start + i] - rh * rinv;
    ad = fmaf(d, d, ad);
  }
  const float dsum = blockReduceSum(ad, sm);
  if (threadIdx.x == 0) atomicAdd(awp_acc, dsum * inv_len);
}

// ---------------------------------------------------------------- kernel B --
__global__ __launch_bounds__(TPB)
void main_kernel(const float* __restrict__ attw, const float* __restrict__ params,
                 const int* __restrict__ labels, const int* __restrict__ lengths,
                 const int* __restrict__ starts, int nseg, int P,
                 float* __restrict__ accs) {
  __shared__ float sm[4];
  if ((int)blockIdx.x < nseg) {
    const int b = blockIdx.x;
    const int len = lengths[b];
    const int start = starts[b];
    const int lab = labels[b];
    if (len == 1024 && (start & 3) == 0)
      seg_body<1>((const float4*)attw, start >> 2, len, lab, &accs[0], sm);
    else if (len == 3072 && (start & 3) == 0)
      seg_body<3>((const float4*)attw, start >> 2, len, lab, &accs[0], sm);
    else
      seg_generic(attw, start, len, lab, &accs[0], sm);
  } else {
    // L1 over params, float4 grid-stride across the param blocks
    const int pb = blockIdx.x - nseg;
    const int npb = gridDim.x - nseg;
    const int P4 = P >> 2;
    const float4* p4 = (const float4*)params;
    float a = 0.0f;
    for (int i = pb * TPB + threadIdx.x; i < P4; i += npb * TPB) {
      float4 v = p4[i];
      a += fabsf(v.x) + fabsf(v.y) + fabsf(v.z) + fabsf(v.w);
    }
    if (pb == 0 && threadIdx.x == 0)
      for (int i = P4 << 2; i < P; i++) a += fabsf(params[i]);
    float tot = blockReduceSum(a, sm);
    if (threadIdx.x == 0) atomicAdd(&accs[1], tot);
  }
}

// ---------------------------------------------------------------- kernel C --
__global__ void finalize_kernel(const float* __restrict__ accs, int nseg,
                                float* __restrict__ out) {
  if (threadIdx.x == 0 && blockIdx.x == 0) {
    const float nll = -accs[2] / (float)nseg;
    const float penalty = 0.5f * 1e-4f * accs[1];        // ALPHA/2 * sum|p|
    const float awp = 0.5f * (accs[0] / (float)nseg);    // BETA/2 * mean(per_seg)
    out[0] = nll + penalty + awp;
    out[1] = nll;
  }
}

extern "C" void kernel_launch(void* const* d_in, const int* in_sizes, int n_in,
                              void* d_out, int out_size, void* d_ws, size_t ws_size,
                              hipStream_t stream) {
  const float* logits  = (const float*)d_in[0];
  const int*   labels  = (const int*)d_in[1];
  const float* attw    = (const float*)d_in[2];
  const float* params  = (const float*)d_in[3];
  // d_in[4]=xpos (recomputed), d_in[5]=segment_ids (unused)
  const int*   lengths = (const int*)d_in[6];
  const int nseg = in_sizes[1];
  const int P    = in_sizes[3];

  float* accs   = (float*)d_ws;
  int*   starts = (int*)((char*)d_ws + 64);
  float* out    = (float*)d_out;

  setup_kernel<<<1, TPB, 0, stream>>>(logits, labels, lengths, nseg, starts, accs);
  const int PARAM_BLOCKS = 256;
  main_kernel<<<nseg + PARAM_BLOCKS, TPB, 0, stream>>>(attw, params, labels, lengths,
                                                       starts, nseg, P, accs);
  finalize_kernel<<<1, 64, 0, stream>>>(accs, nseg, out);
}

// Round 2
// 208.964 us; speedup vs baseline: 1.4215x; 1.4215x over previous
//
#include <hip/hip_runtime.h>

// GuidedAttentionL1Loss on MI355X — round 2.
// R1 lesson: 8448 same-address atomicAdds serialized main_kernel (114 us,
// VALUBusy 10%, 13.5 ns/atomic). Now every block writes its own partial slot;
// finalize reduces. Scan parallelized; NLL moved into the main grid.
//
// Inputs: 0=logits[B,2] f32, 1=labels[B] i32, 2=attention_weights[T] f32,
//         3=params[P] f32, 4=xpos (recomputed), 5=segment_ids (unused),
//         6=lengths[B] i32.  Output: [loss, nll] f32.
//
// ws layout: starts[nseg] (int) at +0; partial[nseg + PARAM_BLOCKS + 1] (float)
// at next 256B boundary. partial[0..nseg)=per-seg awp, [nseg..nseg+PB)=abs
// partials, [nseg+PB]=nll sum.

#define TPB 256
#define PARAM_BLOCKS 256

__device__ __forceinline__ float blockReduceSum(float v, float* sm) {
  #pragma unroll
  for (int off = 32; off > 0; off >>= 1) v += __shfl_down(v, off, 64);
  const int lane = threadIdx.x & 63;
  const int wid  = threadIdx.x >> 6;
  if (lane == 0) sm[wid] = v;
  __syncthreads();
  float s = sm[0] + sm[1] + sm[2] + sm[3];
  __syncthreads();
  return s;
}

// fused two-value reduction: one barrier pair instead of two
__device__ __forceinline__ float2 blockReduceSum2(float a, float b, float* sm) {
  #pragma unroll
  for (int off = 32; off > 0; off >>= 1) {
    a += __shfl_down(a, off, 64);
    b += __shfl_down(b, off, 64);
  }
  const int lane = threadIdx.x & 63;
  const int wid  = threadIdx.x >> 6;
  if (lane == 0) { sm[wid] = a; sm[4 + wid] = b; }
  __syncthreads();
  float2 r;
  r.x = sm[0] + sm[1] + sm[2] + sm[3];
  r.y = sm[4] + sm[5] + sm[6] + sm[7];
  __syncthreads();
  return r;
}

// ---------------------------------------------------------------- kernel A --
// Parallel exclusive scan of lengths -> starts. One block, 256 threads.
__global__ __launch_bounds__(TPB)
void scan_kernel(const int* __restrict__ lengths, int nseg,
                 int* __restrict__ starts) {
  __shared__ int wsum[4];
  const int t = threadIdx.x;
  const int per = (nseg + TPB - 1) / TPB;  // 32 for B=8192
  const int base = t * per;
  int local = 0;
  for (int j = 0; j < per; j++) {
    int idx = base + j;
    if (idx < nseg) local += lengths[idx];
  }
  // wave-level inclusive scan of per-thread sums
  const int lane = t & 63, wid = t >> 6;
  int incl = local;
  #pragma unroll
  for (int off = 1; off < 64; off <<= 1) {
    int n = __shfl_up(incl, off, 64);
    if (lane >= off) incl += n;
  }
  if (lane == 63) wsum[wid] = incl;
  __syncthreads();
  int wbase = 0;
  for (int i = 0; i < wid; i++) wbase += wsum[i];
  int run = wbase + incl - local;  // exclusive prefix for this thread's chunk
  for (int j = 0; j < per; j++) {
    int idx = base + j;
    if (idx < nseg) { starts[idx] = run; run += lengths[idx]; }
  }
}

// ------------------------------------------------------------ segment body --
template <int NC>
__device__ __forceinline__ void seg_body(const float4* __restrict__ w4, int start4,
                                         int len, int lab,
                                         float* __restrict__ out_slot, float* sm) {
  const float inv_len = 1.0f / (float)len;
  float4 wv[NC], rv[NC];
  float aw = 0.0f, axw = 0.0f;
  #pragma unroll
  for (int k = 0; k < NC; k++) {
    const int vi = (k << 8) + threadIdx.x;
    wv[k] = w4[start4 + vi];
    const int i0 = vi << 2;
    aw += wv[k].x + wv[k].y + wv[k].z + wv[k].w;
    axw = fmaf((float)(i0 + 1) * inv_len, wv[k].x, axw);
    axw = fmaf((float)(i0 + 2) * inv_len, wv[k].y, axw);
    axw = fmaf((float)(i0 + 3) * inv_len, wv[k].z, axw);
    axw = fmaf((float)(i0 + 4) * inv_len, wv[k].w, axw);
  }
  const float2 s2 = blockReduceSum2(aw, axw, sm);
  const float mean = s2.y / s2.x;
  const float invstd = (float)len * (lab == 1 ? 1.0f : 0.001f);
  const float rn = 0.39894228040143267f * invstd;  // 1/(std*sqrt(2pi))
  float ar = 0.0f;
  #pragma unroll
  for (int k = 0; k < NC; k++) {
    const int i0 = ((k << 8) + threadIdx.x) << 2;
    float z0 = ((float)(i0 + 1) * inv_len - mean) * invstd;
    float z1 = ((float)(i0 + 2) * inv_len - mean) * invstd;
    float z2 = ((float)(i0 + 3) * inv_len - mean) * invstd;
    float z3 = ((float)(i0 + 4) * inv_len - mean) * invstd;
    rv[k].x = __expf(-0.5f * z0 * z0) * rn;
    rv[k].y = __expf(-0.5f * z1 * z1) * rn;
    rv[k].z = __expf(-0.5f * z2 * z2) * rn;
    rv[k].w = __expf(-0.5f * z3 * z3) * rn;
    ar += rv[k].x + rv[k].y + rv[k].z + rv[k].w;
  }
  const float r_sum = blockReduceSum(ar, sm);
  const float rinv = 1.0f / (r_sum + 1e-6f);
  float ad = 0.0f;
  #pragma unroll
  for (int k = 0; k < NC; k++) {
    float d0 = wv[k].x - rv[k].x * rinv;
    float d1 = wv[k].y - rv[k].y * rinv;
    float d2 = wv[k].z - rv[k].z * rinv;
    float d3 = wv[k].w - rv[k].w * rinv;
    ad = fmaf(d0, d0, ad); ad = fmaf(d1, d1, ad);
    ad = fmaf(d2, d2, ad); ad = fmaf(d3, d3, ad);
  }
  const float dsum = blockReduceSum(ad, sm);
  if (threadIdx.x == 0) *out_slot = dsum * inv_len;
}

// Generic fallback (re-reads w; unused for this dataset's lengths).
__device__ void seg_generic(const float* __restrict__ w, int start, int len, int lab,
                            float* __restrict__ out_slot, float* sm) {
  const float inv_len = 1.0f / (float)len;
  float aw = 0.0f, axw = 0.0f;
  for (int i = threadIdx.x; i < len; i += TPB) {
    float wv = w[start + i];
    aw += wv;
    axw = fmaf((float)(i + 1) * inv_len, wv, axw);
  }
  const float2 s2 = blockReduceSum2(aw, axw, sm);
  const float mean = s2.y / s2.x;
  const float invstd = (float)len * (lab == 1 ? 1.0f : 0.001f);
  const float rn = 0.39894228040143267f * invstd;
  float ar = 0.0f;
  for (int i = threadIdx.x; i < len; i += TPB) {
    float z = ((float)(i + 1) * inv_len - mean) * invstd;
    ar += __expf(-0.5f * z * z) * rn;
  }
  const float r_sum = blockReduceSum(ar, sm);
  const float rinv = 1.0f / (r_sum + 1e-6f);
  float ad = 0.0f;
  for (int i = threadIdx.x; i < len; i += TPB) {
    float z = ((float)(i + 1) * inv_len - mean) * invstd;
    float rh = __expf(-0.5f * z * z) * rn;
    float d = w[start + i] - rh * rinv;
    ad = fmaf(d, d, ad);
  }
  const float dsum = blockReduceSum(ad, sm);
  if (threadIdx.x == 0) *out_slot = dsum * inv_len;
}

// ---------------------------------------------------------------- kernel B --
__global__ __launch_bounds__(TPB)
void main_kernel(const float* __restrict__ attw, const float* __restrict__ params,
                 const float* __restrict__ logits, const int* __restrict__ labels,
                 const int* __restrict__ lengths, const int* __restrict__ starts,
                 int nseg, int P, float* __restrict__ partial) {
  __shared__ float sm[8];
  const int b = blockIdx.x;
  if (b < nseg) {
    const int len = lengths[b];
    const int start = starts[b];
    const int lab = labels[b];
    if (len == 1024 && (start & 3) == 0)
      seg_body<1>((const float4*)attw, start >> 2, len, lab, &partial[b], sm);
    else if (len == 3072 && (start & 3) == 0)
      seg_body<3>((const float4*)attw, start >> 2, len, lab, &partial[b], sm);
    else
      seg_generic(attw, start, len, lab, &partial[b], sm);
  } else if (b < nseg + PARAM_BLOCKS) {
    // L1 over params, float4 grid-stride across the param blocks
    const int pb = b - nseg;
    const int P4 = P >> 2;
    const float4* p4 = (const float4*)params;
    float a = 0.0f;
    for (int i = pb * TPB + threadIdx.x; i < P4; i += PARAM_BLOCKS * TPB) {
      float4 v = p4[i];
      a += fabsf(v.x) + fabsf(v.y) + fabsf(v.z) + fabsf(v.w);
    }
    if (pb == 0 && threadIdx.x == 0)
      for (int i = P4 << 2; i < P; i++) a += fabsf(params[i]);
    float tot = blockReduceSum(a, sm);
    if (threadIdx.x == 0) partial[b] = tot;
  } else {
    // NLL sum block: sum over segments of logp[label] (2-class log-softmax)
    float acc = 0.0f;
    for (int s = threadIdx.x; s < nseg; s += TPB) {
      float l0 = logits[2 * s], l1 = logits[2 * s + 1];
      int lab = labels[s];
      float m = fmaxf(l0, l1);
      float lse = m + logf(expf(l0 - m) + expf(l1 - m));
      acc += (lab ? l1 : l0) - lse;
    }
    float tot = blockReduceSum(acc, sm);
    if (threadIdx.x == 0) partial[b] = tot;
  }
}

// ---------------------------------------------------------------- kernel C --
__global__ __launch_bounds__(TPB)
void finalize_kernel(const float* __restrict__ partial, int nseg,
                     float* __restrict__ out) {
  __shared__ float sm[8];
  float a_awp = 0.0f, a_abs = 0.0f;
  for (int i = threadIdx.x; i < nseg; i += TPB) a_awp += partial[i];
  for (int i = nseg + threadIdx.x; i < nseg + PARAM_BLOCKS; i += TPB)
    a_abs += partial[i];
  const float2 s2 = blockReduceSum2(a_awp, a_abs, sm);
  if (threadIdx.x == 0) {
    const float nll = -partial[nseg + PARAM_BLOCKS] / (float)nseg;
    const float penalty = 0.5f * 1e-4f * s2.y;       // ALPHA/2 * sum|p|
    const float awp = 0.5f * (s2.x / (float)nseg);   // BETA/2 * mean(per_seg)
    out[0] = nll + penalty + awp;
    out[1] = nll;
  }
}

extern "C" void kernel_launch(void* const* d_in, const int* in_sizes, int n_in,
                              void* d_out, int out_size, void* d_ws, size_t ws_size,
                              hipStream_t stream) {
  const float* logits  = (const float*)d_in[0];
  const int*   labels  = (const int*)d_in[1];
  const float* attw    = (const float*)d_in[2];
  const float* params  = (const float*)d_in[3];
  const int*   lengths = (const int*)d_in[6];
  const int nseg = in_sizes[1];
  const int P    = in_sizes[3];

  int*   starts  = (int*)d_ws;
  size_t poff    = ((size_t)nseg * sizeof(int) + 255) & ~(size_t)255;
  float* partial = (float*)((char*)d_ws + poff);
  float* out     = (float*)d_out;

  scan_kernel<<<1, TPB, 0, stream>>>(lengths, nseg, starts);
  main_kernel<<<nseg + PARAM_BLOCKS + 1, TPB, 0, stream>>>(
      attw, params, logits, labels, lengths, starts, nseg, P, partial);
  finalize_kernel<<<1, TPB, 0, stream>>>(partial, nseg, out);
}